// Round 1
// baseline (117.024 us; speedup 1.0000x reference)
//
#include <hip/hip_runtime.h>

// SoftRAM attention: S=128, B=256 bits, H=16 heads, NB=12 bits/neuron, PB=7.
// addr(i,j,h,n) = aq_i | ak_j | ap_{i-j}, disjoint bit groups per (h,n).
//
// R9: register-resident bit-LUT sweep.
//  - __launch_bounds__(1024,4): 128-VGPR budget so all 16 row loads stay in
//    flight (R8 compiled to 56 VGPRs -> staged loads, exposed HBM latency).
//    Loads issued at kernel top; the full drain overlaps token pack and
//    completes at barrier #1 (compiler's vmcnt(0)+s_barrier).
//  - pmask==0 waves (85%): repack the head's 4096 sign bits into a
//    lane-distributed 64x64b register LUT via 64 ballots (read back from the
//    sigma byte-table this wave just wrote). Global bit g=(Lcls<<SB)|Scls.
//    Form A (qb<=6): scan keys j, A ^= LUT-word[kcls_j] fetched with two
//    v_readlane (uniform index, zero LDS traffic), capture prefix at the
//    causal diagonal (j==lane, j==lane+64); r_i = bit qcls_i of capture.
//    Form B (qb>6, kb<=5): C ^= 1<<kcls_j (SALU) + capture; epilogue fetches
//    one LUT row per query via shfl + popc parity. No per-iteration ballots
//    or SALU result chains in either form (2 ballots total per wave).
//  - pmask!=0 waves (block tail): lanes=queries scan, arithmetic causal
//    masks, conflict-free apt reads; ballots only at the end.

#define S 128
#define B 256
#define H 16
#define NB 12

__device__ __forceinline__ unsigned sig(unsigned x) {
    return x ^ ((x >> 3) & 0x70u) ^ ((x >> 6) & 0x70u);
}

__global__ __launch_bounds__(1024, 4) void softram_kernel(
    const int* __restrict__ tokens,        // [S,B] 0/1
    const float* __restrict__ memory,      // [H,B,4096]
    const int* __restrict__ connections,   // [H,B,NB]
    int* __restrict__ out)                 // [S,B] 0/1
{
    const int n    = blockIdx.x;
    const int tid  = threadIdx.x;
    const int h    = tid >> 6;             // wave == head
    const int lane = tid & 63;

    __shared__ unsigned char  bytetab[H * 4096];   // 64 KB sigma-packed signs
    __shared__ unsigned int   tokT[8][S];          // 4 KB transposed token bits
    __shared__ unsigned short akT[H][S];           // key class (fast) / sig(ak) (fb)
    __shared__ unsigned short apt[H][S];           // sig(ap) by dist (fallback only)
    __shared__ int            conns[H][NB];        // 768 B
    __shared__ unsigned int   parts[H][4];         // 128 result bits per head

    // ---- issue own head's 16KB row load first (drains by barrier #1) ----
    const float4* mrow = (const float4*)(memory + ((size_t)(h * 256 + n) << 12));
    float4 va[16];
    #pragma unroll
    for (int t = 0; t < 16; ++t) va[t] = mrow[lane + 64 * t];

    // ---- token pack (transposed: tokT[w][i]) + conns ----
    {
        int i = tid >> 3, w = tid & 7;
        const int4* tp = (const int4*)tokens;
        unsigned v = 0;
        #pragma unroll
        for (int u = 0; u < 8; ++u) {
            int4 x = tp[i * 64 + w * 8 + u];
            v |= (unsigned)(x.x & 1) << (4 * u + 0);
            v |= (unsigned)(x.y & 1) << (4 * u + 1);
            v |= (unsigned)(x.z & 1) << (4 * u + 2);
            v |= (unsigned)(x.w & 1) << (4 * u + 3);
        }
        tokT[w][i] = v;
    }
    if (tid < H * NB) {
        int hh = tid / NB, b = tid - hh * NB;
        conns[hh][b] = connections[hh * (B * NB) + n * NB + b];
    }
    __syncthreads();   // barrier #1: tokT + conns visible (va also drained here)

    // ---- per-head masks (wave-uniform) ----
    unsigned qmask = 0, kmask = 0, pmask = 0;
    #pragma unroll
    for (int b = 0; b < NB; ++b) {
        int c = conns[h][b];
        qmask |= (unsigned)(c < 256) << b;
        kmask |= (unsigned)(c >= 256 && c < 512) << b;
        pmask |= (unsigned)(c >= 512) << b;
    }
    const int qb = __popc(qmask);
    const int kb = __popc(kmask);

    unsigned char* __restrict__ bt = &bytetab[h << 12];
    unsigned long long rlo = 0, rhi = 0;

    if (pmask == 0) {
        // ================= fast path: register bit-LUT =================
        // class tables: akT[h][j] = kcls(j); own query classes in regs
        unsigned qcls0 = 0, qcls1 = 0;
        #pragma unroll
        for (int e = 0; e < 2; ++e) {
            int ii = lane + 64 * e;
            unsigned qc = 0, kc = 0;
            int qn = 0, kn = 0;
            #pragma unroll
            for (int b = 0; b < NB; ++b) {
                int c = conns[h][b];       // wave-uniform -> uniform branches
                if (c < 256) {
                    qc |= ((tokT[c >> 5][ii] >> (c & 31)) & 1u) << qn;
                    ++qn;
                } else {
                    int c2 = c - 256;
                    kc |= ((tokT[c2 >> 5][ii] >> (c2 & 31)) & 1u) << kn;
                    ++kn;
                }
            }
            akT[h][ii] = (unsigned short)kc;
            if (e == 0) qcls0 = qc; else qcls1 = qc;
        }

        // sign pack into sigma-addressed bytes (staging for the repack)
        #pragma unroll
        for (int t = 0; t < 16; ++t) {
            float4 v = va[t];
            unsigned p = 4u * (unsigned)(lane + 64 * t);
            unsigned w = (unsigned)(v.x > 0.f)
                       | ((unsigned)(v.y > 0.f) << 8)
                       | ((unsigned)(v.z > 0.f) << 16)
                       | ((unsigned)(v.w > 0.f) << 24);
            *(unsigned*)&bt[sig(p)] = w;   // sigma keeps bits 0-3 -> aligned dword
        }

        // ---- repack to lane-distributed bit-LUT: lane w holds global bits
        //      g in [64w, 64w+64), g = (Lcls << SBITS) | Scls. ----
        const bool formA = (qb <= 6);          // bit-side = Q if qb<=6 else K
        const int SBITS  = formA ? qb : kb;
        unsigned apl = 0, aul = 0;             // per-lane / per-iter addr parts
        {
            int scnt = 0, lcnt = 0;
            #pragma unroll
            for (int b = 0; b < NB; ++b) {
                int c = conns[h][b];
                bool isS = formA ? (c < 256) : (c >= 256);
                if (isS) {                     // g-bit scnt (< 6) -> lane bit
                    apl |= (((unsigned)lane >> scnt) & 1u) << b;
                    ++scnt;
                } else {
                    int p = SBITS + lcnt;      // g-bit position of this L bit
                    if (p < 6) apl |= (((unsigned)lane >> p) & 1u) << b;
                    else       aul |= (((unsigned)lane >> (p - 6)) & 1u) << b;
                    ++lcnt;
                }
            }
        }
        const unsigned spl  = sig(apl);
        const unsigned saul = sig(aul);        // lane x holds sig(addr) part for it=x
        unsigned Wlo = 0, Whi = 0;
        #pragma unroll 8
        for (int it = 0; it < 64; ++it) {
            unsigned sau  = (unsigned)__builtin_amdgcn_readlane((int)saul, it);
            unsigned bitv = bt[sau ^ spl] & 1u;          // sign at g = it*64+lane
            unsigned long long Bm = __ballot(bitv != 0u);
            Wlo = (lane == it) ? (unsigned)Bm : Wlo;
            Whi = (lane == it) ? (unsigned)(Bm >> 32) : Whi;
        }

        if (formA) {
            // scan keys; A = xor of LUT words of keys seen so far; capture at
            // the causal diagonal. r_i = bit qcls_i of capture.
            unsigned long long A = 0, cap0 = 0, cap1 = 0;
            for (int s8 = 0; s8 < 8; ++s8) {
                uint4 uk = *(const uint4*)&akT[h][s8 * 8];
                #pragma unroll
                for (int t = 0; t < 8; ++t) {
                    int j = s8 * 8 + t;
                    unsigned w = ((const unsigned*)&uk)[t >> 1];
                    unsigned widx = (unsigned)__builtin_amdgcn_readfirstlane(
                        (int)((w >> ((t & 1) * 16)) & 0xffffu));
                    unsigned g0 = widx << qb;
                    int lsel = (int)(g0 >> 6);
                    unsigned lo = (unsigned)__builtin_amdgcn_readlane((int)Wlo, lsel);
                    unsigned hi = (unsigned)__builtin_amdgcn_readlane((int)Whi, lsel);
                    A ^= ((((unsigned long long)hi << 32) | lo) >> (g0 & 63u));
                    cap0 = (lane == j) ? A : cap0;
                }
            }
            for (int s8 = 8; s8 < 16; ++s8) {
                uint4 uk = *(const uint4*)&akT[h][s8 * 8];
                #pragma unroll
                for (int t = 0; t < 8; ++t) {
                    int j = s8 * 8 + t;
                    unsigned w = ((const unsigned*)&uk)[t >> 1];
                    unsigned widx = (unsigned)__builtin_amdgcn_readfirstlane(
                        (int)((w >> ((t & 1) * 16)) & 0xffffu));
                    unsigned g0 = widx << qb;
                    int lsel = (int)(g0 >> 6);
                    unsigned lo = (unsigned)__builtin_amdgcn_readlane((int)Wlo, lsel);
                    unsigned hi = (unsigned)__builtin_amdgcn_readlane((int)Whi, lsel);
                    A ^= ((((unsigned long long)hi << 32) | lo) >> (g0 & 63u));
                    cap1 = (lane == j - 64) ? A : cap1;
                }
            }
            rlo = __ballot(((cap0 >> qcls0) & 1ull) != 0ull);
            rhi = __ballot(((cap1 >> qcls1) & 1ull) != 0ull);
        } else {
            // kb <= 5: C = xor of one-hot key classes (prefix parity word);
            // r_i = parity(LUTrow[qcls_i] & C_i).
            unsigned Cw = 0, cap0 = 0, cap1 = 0;
            for (int s8 = 0; s8 < 8; ++s8) {
                uint4 uk = *(const uint4*)&akT[h][s8 * 8];
                #pragma unroll
                for (int t = 0; t < 8; ++t) {
                    int j = s8 * 8 + t;
                    unsigned w = ((const unsigned*)&uk)[t >> 1];
                    unsigned widx = (unsigned)__builtin_amdgcn_readfirstlane(
                        (int)((w >> ((t & 1) * 16)) & 0xffffu));
                    Cw ^= 1u << widx;
                    cap0 = (lane == j) ? Cw : cap0;
                }
            }
            for (int s8 = 8; s8 < 16; ++s8) {
                uint4 uk = *(const uint4*)&akT[h][s8 * 8];
                #pragma unroll
                for (int t = 0; t < 8; ++t) {
                    int j = s8 * 8 + t;
                    unsigned w = ((const unsigned*)&uk)[t >> 1];
                    unsigned widx = (unsigned)__builtin_amdgcn_readfirstlane(
                        (int)((w >> ((t & 1) * 16)) & 0xffffu));
                    Cw ^= 1u << widx;
                    cap1 = (lane == j - 64) ? Cw : cap1;
                }
            }
            unsigned g0a = qcls0 << kb, g0b = qcls1 << kb;
            unsigned lo0 = (unsigned)__shfl((int)Wlo, (int)(g0a >> 6));
            unsigned hi0 = (unsigned)__shfl((int)Whi, (int)(g0a >> 6));
            unsigned lo1 = (unsigned)__shfl((int)Wlo, (int)(g0b >> 6));
            unsigned hi1 = (unsigned)__shfl((int)Whi, (int)(g0b >> 6));
            unsigned W0 = (unsigned)((((unsigned long long)hi0 << 32) | lo0) >> (g0a & 63u));
            unsigned W1 = (unsigned)((((unsigned long long)hi1 << 32) | lo1) >> (g0b & 63u));
            rlo = __ballot((__popc(W0 & cap0) & 1) != 0);
            rhi = __ballot((__popc(W1 & cap1) & 1) != 0);
        }
    } else {
        // ================= P fallback: lanes = queries =================
        unsigned aqv0 = 0, aqv1 = 0;
        #pragma unroll
        for (int e = 0; e < 2; ++e) {
            int ii = lane + 64 * e;
            unsigned aq = 0, ak = 0, ap = 0;
            #pragma unroll
            for (int b = 0; b < NB; ++b) {
                int c = conns[h][b];
                if (c < 256) {
                    aq |= ((tokT[c >> 5][ii] >> (c & 31)) & 1u) << b;
                } else if (c < 512) {
                    int c2 = c - 256;
                    ak |= ((tokT[c2 >> 5][ii] >> (c2 & 31)) & 1u) << b;
                } else {
                    ap |= (((unsigned)ii >> (c - 512)) & 1u) << b;
                }
            }
            akT[h][ii] = (unsigned short)sig(ak);
            apt[h][ii] = (unsigned short)sig(ap);
            if (e == 0) aqv0 = sig(aq); else aqv1 = sig(aq);
        }

        #pragma unroll
        for (int t = 0; t < 16; ++t) {
            float4 v = va[t];
            unsigned p = 4u * (unsigned)(lane + 64 * t);
            unsigned w = (unsigned)(v.x > 0.f)
                       | ((unsigned)(v.y > 0.f) << 8)
                       | ((unsigned)(v.z > 0.f) << 16)
                       | ((unsigned)(v.w > 0.f) << 24);
            *(unsigned*)&bt[sig(p)] = w;
        }

        // queries i=lane (acc0) and i=lane+64 (acc1); arithmetic causal masks.
        unsigned acc0 = 0, acc1 = 0;
        for (int s8 = 0; s8 < 8; ++s8) {       // j = 0..63
            uint4 uk = *(const uint4*)&akT[h][s8 * 8];
            #pragma unroll
            for (int t = 0; t < 8; ++t) {
                int j = s8 * 8 + t;
                unsigned w = ((const unsigned*)&uk)[t >> 1];
                unsigned akv = (w >> ((t & 1) * 16)) & 0xffffu;
                int d0 = lane - j;             // <0 -> masked out
                unsigned v0 = bt[aqv0 ^ akv ^ (unsigned)apt[h][d0 & 127]] & 1u;
                acc0 ^= (d0 >= 0) ? v0 : 0u;
                int d1 = lane + 64 - j;        // in [1,127]: always active
                unsigned v1 = bt[aqv1 ^ akv ^ (unsigned)apt[h][d1]] & 1u;
                acc1 ^= v1;
            }
        }
        for (int s8 = 8; s8 < 16; ++s8) {      // j = 64..127: only upper query
            uint4 uk = *(const uint4*)&akT[h][s8 * 8];
            #pragma unroll
            for (int t = 0; t < 8; ++t) {
                int j = s8 * 8 + t;
                unsigned w = ((const unsigned*)&uk)[t >> 1];
                unsigned akv = (w >> ((t & 1) * 16)) & 0xffffu;
                int d1 = lane + 64 - j;        // <0 -> masked out
                unsigned v1 = bt[aqv1 ^ akv ^ (unsigned)apt[h][d1 & 127]] & 1u;
                acc1 ^= (d1 >= 0) ? v1 : 0u;
            }
        }
        rlo = __ballot(acc0 != 0u);
        rhi = __ballot(acc1 != 0u);
    }

    if (lane == 0) {
        parts[h][0] = (unsigned)rlo;
        parts[h][1] = (unsigned)(rlo >> 32);
        parts[h][2] = (unsigned)rhi;
        parts[h][3] = (unsigned)(rhi >> 32);
    }
    __syncthreads();   // barrier #2: parts visible

    // ---- majority vote across 16 heads ----
    if (tid < S) {
        int i = tid, tot = 0;
        #pragma unroll
        for (int hh = 0; hh < H; ++hh)
            tot += (parts[hh][i >> 5] >> (i & 31)) & 1;
        out[i * B + n] = (tot > (H / 2)) ? 1 : 0;
    }
}

extern "C" void kernel_launch(void* const* d_in, const int* in_sizes, int n_in,
                              void* d_out, int out_size, void* d_ws, size_t ws_size,
                              hipStream_t stream) {
    const int*   tokens      = (const int*)d_in[0];
    const float* memory      = (const float*)d_in[1];
    const int*   connections = (const int*)d_in[2];
    int*         out         = (int*)d_out;
    (void)in_sizes; (void)n_in; (void)out_size; (void)d_ws; (void)ws_size;

    softram_kernel<<<B, 1024, 0, stream>>>(tokens, memory, connections, out);
}